// Round 10
// baseline (105978.687 us; speedup 1.0000x reference)
//
#include <hip/hip_runtime.h>
#include <hip/hip_bf16.h>
#include <cstdint>
#include <cstddef>
#include <cstring>

using u32 = unsigned int;
typedef _Float16 h2 __attribute__((ext_vector_type(2)));

constexpr int B_=64, T_=600, U_=50, V_=77, H_=400, OUT_=121;
constexpr int NWG=32, THR=512;

// ---- ws byte offsets (shared repacked weights; ~7.5 MB total) ----
constexpr size_t FLAGS_B = 0;                       // 32 slots * 16B
constexpr size_t W1F_B = 1024;                      // [60][1600][4] u32 (K-major pairs)
constexpr size_t W2F_B = W1F_B + 60ull*1600*16;
constexpr size_t W3F_B = W2F_B + 110ull*1600*16;
constexpr size_t WOF_B = W3F_B + 110ull*1600*16;    // [150][128][4] u32
constexpr size_t WWF_B = WOF_B + 150ull*128*16;     // [200][32] u32 (window w, k-major)

struct P {
  const float *x, *tmask, *h0, *c0, *pwv, *pkap;
  const int *text;
  const float *wih1,*whh1,*bih1,*bhh1;
  const float *wih2,*whh2,*bih2,*bhh2;
  const float *wih3,*whh3,*bih3,*bhh3;
  const float *wwin,*bwin,*wout,*bout;
  float *out_y,*out_wv,*out_kap;
  u32 *w1f,*w2f,*w3f,*wof,*wwf;
  u32 *flags;
};

__device__ __forceinline__ u32 ldc_u(const u32* p) {
  return __hip_atomic_load((u32*)p, __ATOMIC_RELAXED, __HIP_MEMORY_SCOPE_AGENT);
}
__device__ __forceinline__ void stc_u(u32* p, u32 v) {
  __hip_atomic_store(p, v, __ATOMIC_RELAXED, __HIP_MEMORY_SCOPE_AGENT);
}
__device__ __forceinline__ float sigm(float x) { return 1.f/(1.f+__expf(-x)); }
__device__ __forceinline__ u32 pkf(float a, float b) {
  auto t = __builtin_amdgcn_cvt_pkrtz(a, b);
  u32 r; memcpy(&r, &t, 4); return r;
}
__device__ __forceinline__ h2 u2h(u32 v) { h2 r; memcpy(&r, &v, 4); return r; }
__device__ __forceinline__ float dot2(h2 a, h2 b, float c) { return __builtin_amdgcn_fdot2(a, b, c, false); }
__device__ __forceinline__ float d4a(uint4 w, uint4 a, float s) {
  s = dot2(u2h(a.x), u2h(w.x), s);
  s = dot2(u2h(a.y), u2h(w.y), s);
  s = dot2(u2h(a.z), u2h(w.z), s);
  s = dot2(u2h(a.w), u2h(w.w), s);
  return s;
}

// weight fetch helpers (K-order definitions)
__device__ __forceinline__ float wval1(const P& p, int r, int j) {
  // L1 K-order: [h1rec 0..399 | wv 400..476 | x 477..479]
  if (j < 400) return p.whh1[(size_t)r*400 + j];
  if (j < 477) return p.wih1[(size_t)r*80 + 3 + (j-400)];
  return p.wih1[(size_t)r*80 + (j-477)];
}
__device__ __forceinline__ float wval23(const float* wih, const float* whh, int r, int j) {
  // K-order: [wv 0..76 | x 77..79 | hin 80..479 | hrec 480..879]
  if (j < 77)  return wih[(size_t)r*480 + 403 + j];
  if (j < 80)  return wih[(size_t)r*480 + (j-77)];
  if (j < 480) return wih[(size_t)r*480 + 3 + (j-80)];
  return whh[(size_t)r*400 + (j-480)];
}

// dual-batch gemv over k-major interleaved weights [g][row1600][16B]
template<int NK>
__device__ __forceinline__ void gemv2(const u32* W, const u32* a0L, const u32* a1L,
                                      float* g0L, float* g1L, int tid) {
  const uint4* Wv  = (const uint4*)W;
  const uint4* av0 = (const uint4*)a0L;
  const uint4* av1 = (const uint4*)a1L;
  float a00=0,a01=0,a02=0, a10=0,a11=0,a12=0, aT0=0,aT1=0;
  const bool t3 = (tid < 64);
#pragma unroll 2
  for (int g = 0; g < NK; ++g) {
    uint4 aA = av0[g];
    uint4 aB = av1[g];
    size_t base = (size_t)g*1600 + tid;
    uint4 w0 = Wv[base];
    uint4 w1 = Wv[base + 512];
    uint4 w2 = Wv[base + 1024];
    a00 = d4a(w0, aA, a00); a10 = d4a(w0, aB, a10);
    a01 = d4a(w1, aA, a01); a11 = d4a(w1, aB, a11);
    a02 = d4a(w2, aA, a02); a12 = d4a(w2, aB, a12);
    if (t3) { uint4 w3 = Wv[base + 1536]; aT0 = d4a(w3, aA, aT0); aT1 = d4a(w3, aB, aT1); }
  }
  g0L[tid] = a00; g0L[512+tid] = a01; g0L[1024+tid] = a02;
  g1L[tid] = a10; g1L[512+tid] = a11; g1L[1024+tid] = a12;
  if (t3) { g0L[1536+tid] = aT0; g1L[1536+tid] = aT1; }
}

__global__ __launch_bounds__(THR) void hw_mono(P p) {
  __shared__ __align__(16) u32 act1[2][240];
  __shared__ __align__(16) u32 act2[2][440];
  __shared__ __align__(16) u32 act3[2][440];
  __shared__ float gatesL[2][1600];
  __shared__ float outP[2][2][128];
  __shared__ float mixP[2][8][32];
  __shared__ float mixe[2][32];
  __shared__ float kapL[2][10];
  __shared__ float phiL[2][64];
  __shared__ float wvf[2][77];
  __shared__ float tmaskL[2][50];
  __shared__ int   textL[2][50];

  const int tid = threadIdx.x;
  const int wg  = blockIdx.x;

  // ---------- one-time shared weight repack (rows [wg*50, wg*50+50)) ----------
  {
    const int r0 = wg*50;
    for (int e = tid; e < 50*60*4; e += THR) {
      int rr = e / 240, rem = e - rr*240;
      int g = rem >> 2, q = rem & 3;
      int r = r0 + rr, j = g*8 + q*2;
      stc_u(p.w1f + ((size_t)g*1600 + r)*4 + q, pkf(wval1(p,r,j), wval1(p,r,j+1)));
    }
    for (int e = tid; e < 50*110*4; e += THR) {
      int rr = e / 440, rem = e - rr*440;
      int g = rem >> 2, q = rem & 3;
      int r = r0 + rr, j = g*8 + q*2;
      stc_u(p.w2f + ((size_t)g*1600 + r)*4 + q,
            pkf(wval23(p.wih2,p.whh2,r,j), wval23(p.wih2,p.whh2,r,j+1)));
      stc_u(p.w3f + ((size_t)g*1600 + r)*4 + q,
            pkf(wval23(p.wih3,p.whh3,r,j), wval23(p.wih3,p.whh3,r,j+1)));
    }
    for (int e = tid; e < 4*150*4; e += THR) {
      int rr = e / 600, rem = e - rr*600;
      int g = rem >> 2, q = rem & 3;
      int c = wg*4 + rr;
      if (c < 121) {
        int j = g*8 + q*2;
        stc_u(p.wof + ((size_t)g*128 + c)*4 + q,
              pkf(p.wout[(size_t)c*1200+j], p.wout[(size_t)c*1200+j+1]));
      }
    }
    for (int e = tid; e < 7*30; e += THR) {
      int kkl = e / 30, m = e - kkl*30;
      int kk = wg*7 + kkl;
      if (kk < 200)
        stc_u(p.wwf + (size_t)kk*32 + m,
              pkf(p.wwin[(size_t)m*400+2*kk], p.wwin[(size_t)m*400+2*kk+1]));
    }
  }
  __syncthreads();                       // drains vmcnt -> repack stores complete
  if (tid == 0) stc_u(p.flags + wg*4, 1u);
  for (int i = tid; i < NWG; i += THR)
    while (ldc_u(p.flags + i*4) == 0) {}
  __syncthreads();
  // From here on: plain cached reads of shared weights; zero cross-wg traffic.

  const int b0g = wg*2;
  for (int e = tid; e < 2*200; e += THR) {
    int bt = e / 200, q = e - bt*200;
    int b = b0g + bt;
    act1[bt][q]     = pkf(p.h0[(size_t)b*H_ + 2*q],        p.h0[(size_t)b*H_ + 2*q+1]);
    act2[bt][240+q] = pkf(p.h0[(size_t)(B_+b)*H_ + 2*q],   p.h0[(size_t)(B_+b)*H_ + 2*q+1]);
    act3[bt][240+q] = pkf(p.h0[(size_t)(2*B_+b)*H_ + 2*q], p.h0[(size_t)(2*B_+b)*H_ + 2*q+1]);
  }
  for (int e = tid; e < 2*77; e += THR) {
    int bt = e / 77, v = e - bt*77;
    wvf[bt][v] = p.pwv[(size_t)(b0g+bt)*V_ + v];
  }
  for (int e = tid; e < 2*50; e += THR) {
    int bt = e / 50, uu = e - bt*50;
    textL[bt][uu]  = p.text[(size_t)(b0g+bt)*U_ + uu];
    tmaskL[bt][uu] = p.tmask[(size_t)(b0g+bt)*U_ + uu];
  }
  for (int e = tid; e < 20; e += THR) {
    int bt = e / 10, k = e - bt*10;
    kapL[bt][k] = p.pkap[(size_t)(b0g+bt)*10 + k];
  }
  float c1[2], c2[2], c3[2], bs1[4], bs2[4], bs3[4];
  if (tid < 400) {
#pragma unroll
    for (int bt = 0; bt < 2; ++bt) {
      int b = b0g + bt;
      c1[bt] = p.c0[(size_t)b*H_ + tid];
      c2[bt] = p.c0[(size_t)(B_+b)*H_ + tid];
      c3[bt] = p.c0[(size_t)(2*B_+b)*H_ + tid];
    }
#pragma unroll
    for (int g = 0; g < 4; ++g) {
      bs1[g] = p.bih1[g*400+tid] + p.bhh1[g*400+tid];
      bs2[g] = p.bih2[g*400+tid] + p.bhh2[g*400+tid];
      bs3[g] = p.bih3[g*400+tid] + p.bhh3[g*400+tid];
    }
  }
  __syncthreads();

  for (int t = 0; t < T_; ++t) {
    // S1: act1 tail = [wv(t-1) | x(t)]
    if (tid < 80) {
      int bt = tid / 40, q = tid - bt*40;
      const float* xb = p.x + ((size_t)(b0g+bt)*T_ + t)*3;
      float f0, f1;
      if (q < 38)       { f0 = wvf[bt][2*q]; f1 = wvf[bt][2*q+1]; }
      else if (q == 38) { f0 = wvf[bt][76];  f1 = xb[0]; }
      else              { f0 = xb[1];        f1 = xb[2]; }
      act1[bt][200+q] = pkf(f0, f1);
    }
    __syncthreads();
    gemv2<60>(p.w1f, act1[0], act1[1], gatesL[0], gatesL[1], tid);
    __syncthreads();
    // cell1 -> h1 pairs into act2[40..239] (this t) and act1[0..199] (next t)
    if (tid < 400) {
#pragma unroll
      for (int bt = 0; bt < 2; ++bt) {
        float gi = gatesL[bt][tid]      + bs1[0];
        float gf = gatesL[bt][400+tid]  + bs1[1];
        float gg = gatesL[bt][800+tid]  + bs1[2];
        float go = gatesL[bt][1200+tid] + bs1[3];
        float cn = sigm(gf)*c1[bt] + sigm(gi)*tanhf(gg);
        c1[bt] = cn;
        float h = sigm(go)*tanhf(cn);
        float hb = __shfl_down(h, 1, 64);
        if (!(tid & 1)) {
          u32 pk = pkf(h, hb);
          act2[bt][40 + (tid>>1)] = pk;
          act1[bt][tid>>1] = pk;
        }
      }
    }
    __syncthreads();
    // attention: mix partials
    if (tid < 480) {
      int bt = tid / 240, r = tid - bt*240;
      int seg = r / 30, m = r - seg*30;
      const u32* hp = &act2[bt][40];
      float d = 0.f;
      int k0 = seg*25;
#pragma unroll 5
      for (int kk = k0; kk < k0+25; ++kk)
        d = dot2(u2h(hp[kk]), u2h(p.wwf[(size_t)kk*32 + m]), d);
      mixP[bt][seg][m] = d;
    }
    __syncthreads();
    if (tid < 60) {
      int bt = tid / 30, m = tid - bt*30;
      float s = 0.f;
#pragma unroll
      for (int sg = 0; sg < 8; ++sg) s += mixP[bt][sg][m];
      mixe[bt][m] = __expf(s + p.bwin[m]);
    }
    __syncthreads();
    if (tid < 20) {
      int bt = tid / 10, k = tid - bt*10;
      kapL[bt][k] += mixe[bt][20+k];
      if (t == T_-1) p.out_kap[(size_t)(b0g+bt)*10 + k] = kapL[bt][k];
    }
    __syncthreads();
    if (tid < 100) {
      int bt = tid / 50, uu = tid - bt*50;
      float s = 0.f; const float fu = (float)uu;
#pragma unroll
      for (int k = 0; k < 10; ++k) {
        float df = kapL[bt][k] - fu;
        s += mixe[bt][k] * __expf(-mixe[bt][10+k]*df*df);
      }
      phiL[bt][uu] = s * tmaskL[bt][uu];
    }
    __syncthreads();
    if (tid < 154) {
      int bt = tid / 77, v = tid - bt*77;
      float s = 0.f;
      for (int uu = 0; uu < U_; ++uu)
        if (textL[bt][uu] == v) s += phiL[bt][uu];
      wvf[bt][v] = s;
      p.out_wv[((size_t)(b0g+bt)*T_ + t)*V_ + v] = s;
    }
    __syncthreads();
    // wvx(t) heads for act2/act3
    if (tid < 80) {
      int bt = tid / 40, q = tid - bt*40;
      const float* xb = p.x + ((size_t)(b0g+bt)*T_ + t)*3;
      float f0, f1;
      if (q < 38)       { f0 = wvf[bt][2*q]; f1 = wvf[bt][2*q+1]; }
      else if (q == 38) { f0 = wvf[bt][76];  f1 = xb[0]; }
      else              { f0 = xb[1];        f1 = xb[2]; }
      u32 pk = pkf(f0, f1);
      act2[bt][q] = pk; act3[bt][q] = pk;
    }
    __syncthreads();
    gemv2<110>(p.w2f, act2[0], act2[1], gatesL[0], gatesL[1], tid);
    __syncthreads();
    if (tid < 400) {  // cell2 -> act2[240..439] (rec) + act3[40..239] (feed)
#pragma unroll
      for (int bt = 0; bt < 2; ++bt) {
        float gi = gatesL[bt][tid]      + bs2[0];
        float gf = gatesL[bt][400+tid]  + bs2[1];
        float gg = gatesL[bt][800+tid]  + bs2[2];
        float go = gatesL[bt][1200+tid] + bs2[3];
        float cn = sigm(gf)*c2[bt] + sigm(gi)*tanhf(gg);
        c2[bt] = cn;
        float h = sigm(go)*tanhf(cn);
        float hb = __shfl_down(h, 1, 64);
        if (!(tid & 1)) {
          u32 pk = pkf(h, hb);
          act2[bt][240 + (tid>>1)] = pk;
          act3[bt][40 + (tid>>1)] = pk;
        }
      }
    }
    __syncthreads();
    gemv2<110>(p.w3f, act3[0], act3[1], gatesL[0], gatesL[1], tid);
    __syncthreads();
    if (tid < 400) {  // cell3 -> act3[240..439]
#pragma unroll
      for (int bt = 0; bt < 2; ++bt) {
        float gi = gatesL[bt][tid]      + bs3[0];
        float gf = gatesL[bt][400+tid]  + bs3[1];
        float gg = gatesL[bt][800+tid]  + bs3[2];
        float go = gatesL[bt][1200+tid] + bs3[3];
        float cn = sigm(gf)*c3[bt] + sigm(gi)*tanhf(gg);
        c3[bt] = cn;
        float h = sigm(go)*tanhf(cn);
        float hb = __shfl_down(h, 1, 64);
        if (!(tid & 1)) act3[bt][240 + (tid>>1)] = pkf(h, hb);
      }
    }
    __syncthreads();
    // OUT: y = [h1|h2|h3] @ wout^T + bout  (h1,h2 contiguous in act2[40..439]; h3 in act3[240..439])
    {
      int bt = tid >> 8, seg = (tid >> 7) & 1, c = tid & 127;
      float s = 0.f;
      if (c < 121) {
        const uint4* Wv = (const uint4*)p.wof;
        int g0 = seg*75, g1 = g0 + 75;
        for (int g = g0; g < g1; ++g) {
          const u32* bp = (g < 100) ? &act2[bt][40 + 4*g] : &act3[bt][4*g - 160];
          uint4 a = *(const uint4*)bp;
          uint4 w = Wv[(size_t)g*128 + c];
          s = d4a(w, a, s);
        }
      }
      outP[bt][seg][c] = s;
    }
    __syncthreads();
    if (tid < 242) {
      int bt = tid / 121, c = tid - bt*121;
      p.out_y[((size_t)(b0g+bt)*T_ + t)*OUT_ + c] = outP[bt][0][c] + outP[bt][1][c] + p.bout[c];
    }
    __syncthreads();
  }
}

extern "C" void kernel_launch(void* const* d_in, const int* in_sizes, int n_in,
                              void* d_out, int out_size, void* d_ws, size_t ws_size,
                              hipStream_t stream) {
  (void)in_sizes; (void)n_in; (void)out_size; (void)ws_size;
  P p;
  p.x = (const float*)d_in[0];
  p.text = (const int*)d_in[1];
  p.tmask = (const float*)d_in[2];
  p.h0 = (const float*)d_in[3];
  p.c0 = (const float*)d_in[4];
  p.pwv = (const float*)d_in[5];
  p.pkap = (const float*)d_in[6];
  p.wih1 = (const float*)d_in[7];  p.whh1 = (const float*)d_in[8];
  p.bih1 = (const float*)d_in[9];  p.bhh1 = (const float*)d_in[10];
  p.wih2 = (const float*)d_in[11]; p.whh2 = (const float*)d_in[12];
  p.bih2 = (const float*)d_in[13]; p.bhh2 = (const float*)d_in[14];
  p.wih3 = (const float*)d_in[15]; p.whh3 = (const float*)d_in[16];
  p.bih3 = (const float*)d_in[17]; p.bhh3 = (const float*)d_in[18];
  p.wwin = (const float*)d_in[19]; p.bwin = (const float*)d_in[20];
  p.wout = (const float*)d_in[21]; p.bout = (const float*)d_in[22];
  float* out = (float*)d_out;
  p.out_y  = out;
  p.out_wv = out + (size_t)B_*T_*OUT_;
  p.out_kap = p.out_wv + (size_t)B_*T_*V_;
  char* ws = (char*)d_ws;
  p.flags = (u32*)(ws + FLAGS_B);
  p.w1f = (u32*)(ws + W1F_B);
  p.w2f = (u32*)(ws + W2F_B);
  p.w3f = (u32*)(ws + W3F_B);
  p.wof = (u32*)(ws + WOF_B);
  p.wwf = (u32*)(ws + WWF_B);
  (void)hipMemsetAsync(ws + FLAGS_B, 0, NWG*16, stream);
  hipLaunchKernelGGL(hw_mono, dim3(NWG), dim3(THR), 0, stream, p);
}

// Round 11
// 59902.716 us; speedup vs baseline: 1.7692x; 1.7692x over previous
//
#include <hip/hip_runtime.h>
#include <hip/hip_bf16.h>
#include <cstdint>
#include <cstddef>
#include <cstring>

using u32 = unsigned int;
typedef _Float16 h2v __attribute__((ext_vector_type(2)));

constexpr int B_=64, T_=600, U_=50, V_=77, H_=400, OUT_=121;
constexpr int NBLK=48, THR=512, RD=4;

// flag stages: 0=F1, 1=F2a, 2=F2b, 3=F3a, 4=F3b ; startup slots at 24000+
constexpr int SS = 5*600*8;
constexpr size_t FLAGS_B = 0;
constexpr size_t FLAGS_SZ = (size_t)(SS + 64)*16;        // 385,024
constexpr size_t W1F_B = FLAGS_SZ;                       // [60][1600][16B]
constexpr size_t W2F_B = W1F_B + 60ull*1600*16;          // [110][1600][16B]
constexpr size_t W3F_B = W2F_B + 110ull*1600*16;
constexpr size_t WOF_B = W3F_B + 110ull*1600*16;         // [150][128][16B]
constexpr size_t WWF_B = WOF_B + 150ull*128*16;          // u32 [30][200] m-major
constexpr size_t FWV_B = WWF_B + 30ull*200*4;            // u32 [600][64][40]
constexpr size_t FH1_B = FWV_B + 600ull*64*40*4;         // u32 [600][64][200]
constexpr size_t FH2_B = FH1_B + 600ull*64*200*4;
constexpr size_t FH3_B = FH2_B + 600ull*64*200*4;
constexpr size_t PG2_B = FH3_B + 600ull*64*200*4;        // f32 ring [RD][64][1600]
constexpr size_t PG3_B = PG2_B + (size_t)RD*64*1600*4;
// total ~109.5 MB

struct P {
  const float *x, *tmask, *h0, *c0, *pwv, *pkap;
  const int *text;
  const float *wih1,*whh1,*bih1,*bhh1;
  const float *wih2,*whh2,*bih2,*bhh2;
  const float *wih3,*whh3,*bih3,*bhh3;
  const float *wwin,*bwin,*wout,*bout;
  float *out_y,*out_wv,*out_kap;
  u32 *w1f,*w2f,*w3f,*wof,*wwf;
  u32 *fwv,*fh1,*fh2,*fh3,*pg2,*pg3;
  u32 *flags;
};

__device__ __forceinline__ u32 ldc_u(const u32* p) {
  return __hip_atomic_load((u32*)p, __ATOMIC_RELAXED, __HIP_MEMORY_SCOPE_AGENT);
}
__device__ __forceinline__ void stc_u(u32* p, u32 v) {
  __hip_atomic_store(p, v, __ATOMIC_RELAXED, __HIP_MEMORY_SCOPE_AGENT);
}
__device__ __forceinline__ float sigm(float x) { return 1.f/(1.f+__expf(-x)); }
__device__ __forceinline__ u32 pkf(float a, float b) {
  auto t = __builtin_amdgcn_cvt_pkrtz(a, b);
  u32 r; memcpy(&r, &t, 4); return r;
}
__device__ __forceinline__ h2v uh(u32 v) { h2v r; memcpy(&r, &v, 4); return r; }
__device__ __forceinline__ u32 f2u(float f) { u32 r; memcpy(&r, &f, 4); return r; }
__device__ __forceinline__ float u2f(u32 v) { float r; memcpy(&r, &v, 4); return r; }
__device__ __forceinline__ float dot2(h2v a, h2v b, float c) { return __builtin_amdgcn_fdot2(a, b, c, false); }
__device__ __forceinline__ float d4a(uint4 w, uint4 a, float s) {
  s = dot2(uh(a.x), uh(w.x), s); s = dot2(uh(a.y), uh(w.y), s);
  s = dot2(uh(a.z), uh(w.z), s); s = dot2(uh(a.w), uh(w.w), s);
  return s;
}

__device__ __forceinline__ u32* flg(const P& p, int stage, int t, int g) {
  return p.flags + ((size_t)(stage*600 + t)*8 + g)*4;
}
__device__ __forceinline__ void poll1(const P& p, int stage, int t, int g) {
  while (ldc_u(flg(p, stage, t, g)) == 0) {}
}

// weight K-order sources (validated R9/R10)
__device__ __forceinline__ float wval1(const P& p, int r, int j) {
  if (j < 400) return p.whh1[(size_t)r*400 + j];
  if (j < 477) return p.wih1[(size_t)r*80 + 3 + (j-400)];
  return p.wih1[(size_t)r*80 + (j-477)];
}
__device__ __forceinline__ float wval23(const float* wih, const float* whh, int r, int j) {
  if (j < 77)  return wih[(size_t)r*480 + 403 + j];
  if (j < 80)  return wih[(size_t)r*480 + (j-77)];
  if (j < 480) return wih[(size_t)r*480 + 3 + (j-80)];
  return whh[(size_t)r*400 + (j-480)];
}

// unit-mapped gemv: thread u<400 accumulates rows {u,400+u,800+u,1200+u}
template<int NG>
__device__ __forceinline__ void gemv_u(const uint4* Wv, int G0, const uint4* actv,
                                       int u, float acc[4][8]) {
#pragma unroll 2
  for (int g = 0; g < NG; ++g) {
    size_t base = (size_t)(G0+g)*1600 + u;
    uint4 w0 = Wv[base], w1 = Wv[base+400], w2 = Wv[base+800], w3 = Wv[base+1200];
#pragma unroll
    for (int b = 0; b < 8; ++b) {
      uint4 a = actv[b*64 + g];
      acc[0][b]=d4a(w0,a,acc[0][b]); acc[1][b]=d4a(w1,a,acc[1][b]);
      acc[2][b]=d4a(w2,a,acc[2][b]); acc[3][b]=d4a(w3,a,acc[3][b]);
    }
  }
}
// row-mapped gemv: thread owns rows {tid, tid+512, tid+1024} (+1536+tid if tid<64)
template<int NG>
__device__ __forceinline__ void gemv_r(const uint4* Wv, const uint4* actv,
                                       int tid, float acc[4][8], bool r4) {
#pragma unroll 2
  for (int g = 0; g < NG; ++g) {
    size_t base = (size_t)g*1600 + tid;
    uint4 w0 = Wv[base], w1 = Wv[base+512], w2 = Wv[base+1024];
    uint4 w3 = r4 ? Wv[base+1536] : w0;
#pragma unroll
    for (int b = 0; b < 8; ++b) {
      uint4 a = actv[b*64 + g];
      acc[0][b]=d4a(w0,a,acc[0][b]); acc[1][b]=d4a(w1,a,acc[1][b]);
      acc[2][b]=d4a(w2,a,acc[2][b]); if (r4) acc[3][b]=d4a(w3,a,acc[3][b]);
    }
  }
}

// ================= L1 + attention (batch-local, fully intra-wg recurrence) =====
__device__ void l1_role(const P& p, int g, char* smem) {
  const int tid = threadIdx.x;
  const int B0 = g*8;
  u32* act1 = (u32*)smem;                       // [8][256]: head 0..199 = h1 pairs, tail 200..239 = wvx
  float* wvf   = (float*)(smem + 8192);         // [8][80]
  float* mixe  = (float*)(smem + 10752);        // [8][32]
  float* kapL  = (float*)(smem + 11776);        // [8][12]
  float* phiL  = (float*)(smem + 12160);        // [8][52]
  int*   textL = (int*)(smem + 13824);          // [8][52]
  float* tmaskL= (float*)(smem + 15488);        // [8][52]
  const uint4* Wv = (const uint4*)p.w1f;
  const uint4* actv = (const uint4*)act1;
  const uint4* wwfv = (const uint4*)p.wwf;      // [30][50]

  for (int e = tid; e < 8*200; e += THR) {
    int b = e/200, q = e - b*200;
    act1[b*256 + q] = pkf(p.h0[(size_t)(B0+b)*H_ + 2*q], p.h0[(size_t)(B0+b)*H_ + 2*q + 1]);
  }
  for (int e = tid; e < 8*77; e += THR) {
    int b = e/77, v = e - b*77;
    wvf[b*80 + v] = p.pwv[(size_t)(B0+b)*V_ + v];
  }
  for (int e = tid; e < 8*50; e += THR) {
    int b = e/50, uu = e - b*50;
    textL[b*52 + uu]  = p.text[(size_t)(B0+b)*U_ + uu];
    tmaskL[b*52 + uu] = p.tmask[(size_t)(B0+b)*U_ + uu];
  }
  for (int e = tid; e < 80; e += THR) {
    int b = e/10, k = e - b*10;
    kapL[b*12 + k] = p.pkap[(size_t)(B0+b)*10 + k];
  }
  float c1[8], bs[4];
  if (tid < 400) {
#pragma unroll
    for (int b = 0; b < 8; ++b) c1[b] = p.c0[(size_t)(B0+b)*H_ + tid];
#pragma unroll
    for (int gg = 0; gg < 4; ++gg) bs[gg] = p.bih1[gg*400+tid] + p.bhh1[gg*400+tid];
  }
  __syncthreads();

  for (int t = 0; t < T_; ++t) {
    // tail: [wv(t-1) | x(t)]
    if (tid < 320) {
      int b = tid/40, q = tid - b*40;
      const float* xb = p.x + ((size_t)(B0+b)*T_ + t)*3;
      float f0, f1;
      if (q < 38)       { f0 = wvf[b*80 + 2*q]; f1 = wvf[b*80 + 2*q + 1]; }
      else if (q == 38) { f0 = wvf[b*80 + 76];  f1 = xb[0]; }
      else              { f0 = xb[1];           f1 = xb[2]; }
      act1[b*256 + 200 + q] = pkf(f0, f1);
    }
    __syncthreads();
    float acc[4][8] = {};
    if (tid < 400) gemv_u<60>(Wv, 0, actv, tid, acc);
    __syncthreads();
    // cell + store h1 pairs (LDS head + global fh1)
    if (tid < 400) {
#pragma unroll
      for (int b = 0; b < 8; ++b) {
        float gi=acc[0][b]+bs[0], gf=acc[1][b]+bs[1], gg=acc[2][b]+bs[2], go=acc[3][b]+bs[3];
        float cn = sigm(gf)*c1[b] + sigm(gi)*tanhf(gg);
        c1[b] = cn;
        float h = sigm(go)*tanhf(cn);
        float hb = __shfl_down(h, 1, 64);
        if (!(tid & 1)) {
          u32 pk = pkf(h, hb);
          act1[b*256 + (tid>>1)] = pk;
          stc_u(p.fh1 + ((size_t)t*64 + B0+b)*200 + (tid>>1), pk);
        }
      }
    } else {
      for (int e = tid - 400; e < 8*77; e += 112) {
        int b = e/77, v = e - b*77;
        wvf[b*80 + v] = 0.f;
      }
    }
    __syncthreads();
    // window mix
    if (tid < 240) {
      int b = tid/30, m = tid - b*30;
      float d = 0.f;
#pragma unroll 2
      for (int kk = 0; kk < 50; ++kk)
        d = d4a(wwfv[m*50 + kk], actv[b*64 + kk], d);
      mixe[b*32 + m] = __expf(d + p.bwin[m]);
    }
    __syncthreads();
    if (tid < 80) {
      int b = tid/10, k = tid - b*10;
      kapL[b*12 + k] += mixe[b*32 + 20 + k];
      if (t == T_-1) p.out_kap[(size_t)(B0+b)*10 + k] = kapL[b*12 + k];
    }
    __syncthreads();
    if (tid < 400) {
      int b = tid/50, uu = tid - b*50;
      float s = 0.f; const float fu = (float)uu;
#pragma unroll
      for (int k = 0; k < 10; ++k) {
        float df = kapL[b*12 + k] - fu;
        s += mixe[b*32 + k] * __expf(-mixe[b*32 + 10 + k]*df*df);
      }
      phiL[b*52 + uu] = s * tmaskL[b*52 + uu];
    }
    __syncthreads();
    if (tid < 8) {
      for (int uu = 0; uu < U_; ++uu)
        wvf[tid*80 + textL[tid*52 + uu]] += phiL[tid*52 + uu];
    }
    __syncthreads();
    for (int e = tid; e < 8*77; e += THR) {
      int b = e/77, v = e - b*77;
      p.out_wv[((size_t)(B0+b)*T_ + t)*V_ + v] = wvf[b*80 + v];
    }
    if (tid < 320) {
      int b = tid/40, q = tid - b*40;
      const float* xb = p.x + ((size_t)(B0+b)*T_ + t)*3;
      float f0, f1;
      if (q < 38)       { f0 = wvf[b*80 + 2*q]; f1 = wvf[b*80 + 2*q + 1]; }
      else if (q == 38) { f0 = wvf[b*80 + 76];  f1 = xb[0]; }
      else              { f0 = xb[1];           f1 = xb[2]; }
      stc_u(p.fwv + ((size_t)t*64 + B0+b)*40 + q, pkf(f0, f1));
    }
    __syncthreads();
    if (tid == 0) stc_u(flg(p, 0, t, g), 1u);
  }
}

// ================= feed-forward half stage (L2a / L3a) ========================
__device__ void a_role(const P& p, int g, char* smem, const u32* W, const u32* hin,
                       u32* pg, int inStage, int bpStage, int outStage) {
  const int tid = threadIdx.x;
  const int B0 = g*8;
  u32* actL = (u32*)smem;                 // [8][256]
  const uint4* Wv = (const uint4*)W;
  const uint4* actv = (const uint4*)actL;
  const bool r4 = (tid < 64);

  for (int t = 0; t < T_; ++t) {
    if (tid == 0) {
      poll1(p, inStage, t, g);
      if (t >= RD) poll1(p, bpStage, t-RD, g);
    }
    __syncthreads();
    for (int e = tid; e < 8*240; e += THR) {
      int b = e/240, pl = e - b*240;
      u32 v = (pl < 40) ? p.fwv[((size_t)t*64 + B0+b)*40 + pl]
                        : hin[((size_t)t*64 + B0+b)*200 + (pl-40)];
      actL[b*256 + pl] = v;
    }
    __syncthreads();
    float acc[4][8] = {};
    gemv_r<60>(Wv, actv, tid, acc, r4);
    const int slot = t & (RD-1);
#pragma unroll
    for (int b = 0; b < 8; ++b) {
      size_t rb = ((size_t)slot*64 + B0+b)*1600;
      stc_u(pg + rb + tid,        f2u(acc[0][b]));
      stc_u(pg + rb + tid + 512,  f2u(acc[1][b]));
      stc_u(pg + rb + tid + 1024, f2u(acc[2][b]));
      if (r4) stc_u(pg + rb + tid + 1536, f2u(acc[3][b]));
    }
    __syncthreads();
    if (tid == 0) stc_u(flg(p, outStage, t, g), 1u);
  }
}

// ================= recurrent half stage (L2b / L3b) ===========================
__device__ void b_role(const P& p, int g, char* smem, const u32* W, const u32* pg,
                       u32* recOut, int layer, const float* bih, const float* bhh,
                       int inStage, int outStage) {
  const int tid = threadIdx.x;
  const int B0 = g*8;
  u32* actrec = (u32*)smem;               // [8][256], pairs 0..199 = h(t-1)
  const uint4* Wv = (const uint4*)W;
  const uint4* actv = (const uint4*)actrec;

  for (int e = tid; e < 8*200; e += THR) {
    int b = e/200, q = e - b*200;
    const float* h0l = p.h0 + (size_t)layer*B_*H_ + (size_t)(B0+b)*H_;
    actrec[b*256 + q] = pkf(h0l[2*q], h0l[2*q+1]);
  }
  float cc[8], bs[4];
  if (tid < 400) {
#pragma unroll
    for (int b = 0; b < 8; ++b)
      cc[b] = p.c0[(size_t)layer*B_*H_ + (size_t)(B0+b)*H_ + tid];
#pragma unroll
    for (int gg = 0; gg < 4; ++gg) bs[gg] = bih[gg*400+tid] + bhh[gg*400+tid];
  }
  __syncthreads();

  for (int t = 0; t < T_; ++t) {
    if (tid == 0) poll1(p, inStage, t, g);
    __syncthreads();
    float acc[4][8];
    if (tid < 400) {
      const int slot = t & (RD-1);
#pragma unroll
      for (int i = 0; i < 4; ++i)
#pragma unroll
        for (int b = 0; b < 8; ++b)
          acc[i][b] = u2f(ldc_u(pg + ((size_t)slot*64 + B0+b)*1600 + i*400 + tid));
      gemv_u<50>(Wv, 60, actv, tid, acc);
    }
    __syncthreads();
    if (tid < 400) {
#pragma unroll
      for (int b = 0; b < 8; ++b) {
        float gi=acc[0][b]+bs[0], gf=acc[1][b]+bs[1], gg=acc[2][b]+bs[2], go=acc[3][b]+bs[3];
        float cn = sigm(gf)*cc[b] + sigm(gi)*tanhf(gg);
        cc[b] = cn;
        float h = sigm(go)*tanhf(cn);
        float hb = __shfl_down(h, 1, 64);
        if (!(tid & 1)) {
          u32 pk = pkf(h, hb);
          actrec[b*256 + (tid>>1)] = pk;
          stc_u(recOut + ((size_t)t*64 + B0+b)*200 + (tid>>1), pk);
        }
      }
    }
    __syncthreads();
    if (tid == 0) stc_u(flg(p, outStage, t, g), 1u);
  }
}

// ================= output projection ==========================================
__device__ void out_role(const P& p, int g, char* smem) {
  const int tid = threadIdx.x;
  const int B0 = g*8;
  u32* actL = (u32*)smem;                 // [8][600]
  const uint4* Wv = (const uint4*)p.wof;
  const uint4* actv = (const uint4*)actL; // [8][150]
  const int c = tid & 127, bq = tid >> 7;
  float bo = (c < 121) ? p.bout[c] : 0.f;

  for (int t = 0; t < T_; ++t) {
    if (tid == 0) poll1(p, 4, t, g);
    __syncthreads();
    for (int e = tid; e < 8*600; e += THR) {
      int b = e/600, P = e - b*600;
      u32 v;
      if (P < 200)      v = p.fh1[((size_t)t*64 + B0+b)*200 + P];
      else if (P < 400) v = p.fh2[((size_t)t*64 + B0+b)*200 + (P-200)];
      else              v = p.fh3[((size_t)t*64 + B0+b)*200 + (P-400)];
      actL[b*600 + P] = v;
    }
    __syncthreads();
    if (c < 121) {
      float a0 = 0.f, a1 = 0.f;
      const int b0 = bq*2;
#pragma unroll 2
      for (int g2 = 0; g2 < 150; ++g2) {
        uint4 w = Wv[(size_t)g2*128 + c];
        a0 = d4a(w, actv[b0*150 + g2], a0);
        a1 = d4a(w, actv[(b0+1)*150 + g2], a1);
      }
      p.out_y[((size_t)(B0+b0)*T_ + t)*OUT_ + c]   = a0 + bo;
      p.out_y[((size_t)(B0+b0+1)*T_ + t)*OUT_ + c] = a1 + bo;
    }
    __syncthreads();
  }
}

__global__ __launch_bounds__(THR, 2) void hw_pipe2(P p) {
  __shared__ __align__(16) char smem[20480];
  const int wg = blockIdx.x, tid = threadIdx.x;

  // ---- startup: cooperative shared-weight repack + handshake (R10 pattern) ----
  {
    const int r0 = wg*34;
    for (int e = tid; e < 34*240; e += THR) {
      int rr = e/240, rem = e - rr*240;
      int r = r0 + rr; if (r >= 1600) break;
      int gg = rem >> 2, q = rem & 3, j = gg*8 + q*2;
      stc_u(p.w1f + ((size_t)gg*1600 + r)*4 + q, pkf(wval1(p,r,j), wval1(p,r,j+1)));
    }
    for (int e = tid; e < 34*440; e += THR) {
      int rr = e/440, rem = e - rr*440;
      int r = r0 + rr; if (r >= 1600) break;
      int gg = rem >> 2, q = rem & 3, j = gg*8 + q*2;
      stc_u(p.w2f + ((size_t)gg*1600 + r)*4 + q,
            pkf(wval23(p.wih2,p.whh2,r,j), wval23(p.wih2,p.whh2,r,j+1)));
      stc_u(p.w3f + ((size_t)gg*1600 + r)*4 + q,
            pkf(wval23(p.wih3,p.whh3,r,j), wval23(p.wih3,p.whh3,r,j+1)));
    }
    for (int e = tid; e < 3*600; e += THR) {
      int cc = e/600, rem = e - cc*600;
      int cI = wg*3 + cc; if (cI >= 121) break;
      int gg = rem >> 2, q = rem & 3, j = gg*8 + q*2;
      stc_u(p.wof + ((size_t)gg*128 + cI)*4 + q,
            pkf(p.wout[(size_t)cI*1200 + j], p.wout[(size_t)cI*1200 + j + 1]));
    }
    for (int e = tid; e < 5*30; e += THR) {
      int kkl = e/30, m = e - kkl*30;
      int kk = wg*5 + kkl;
      if (kk < 200)
        stc_u(p.wwf + (size_t)m*200 + kk,
              pkf(p.wwin[(size_t)m*400 + 2*kk], p.wwin[(size_t)m*400 + 2*kk + 1]));
    }
  }
  __syncthreads();
  if (tid == 0) stc_u(p.flags + (size_t)(SS + wg)*4, 1u);
  for (int i = tid; i < NBLK; i += THR)
    while (ldc_u(p.flags + (size_t)(SS + i)*4) == 0) {}
  __syncthreads();

  const int role = wg >> 3, g = wg & 7;
  if (role == 0)      l1_role(p, g, smem);
  else if (role == 1) a_role(p, g, smem, p.w2f, p.fh1, p.pg2, 0, 2, 1);
  else if (role == 2) b_role(p, g, smem, p.w2f, p.pg2, p.fh2, 1, p.bih2, p.bhh2, 1, 2);
  else if (role == 3) a_role(p, g, smem, p.w3f, p.fh2, p.pg3, 2, 4, 3);
  else if (role == 4) b_role(p, g, smem, p.w3f, p.pg3, p.fh3, 2, p.bih3, p.bhh3, 3, 4);
  else                out_role(p, g, smem);
}

extern "C" void kernel_launch(void* const* d_in, const int* in_sizes, int n_in,
                              void* d_out, int out_size, void* d_ws, size_t ws_size,
                              hipStream_t stream) {
  (void)in_sizes; (void)n_in; (void)out_size; (void)ws_size;
  P p;
  p.x = (const float*)d_in[0];
  p.text = (const int*)d_in[1];
  p.tmask = (const float*)d_in[2];
  p.h0 = (const float*)d_in[3];
  p.c0 = (const float*)d_in[4];
  p.pwv = (const float*)d_in[5];
  p.pkap = (const float*)d_in[6];
  p.wih1 = (const float*)d_in[7];  p.whh1 = (const float*)d_in[8];
  p.bih1 = (const float*)d_in[9];  p.bhh1 = (const float*)d_in[10];
  p.wih2 = (const float*)d_in[11]; p.whh2 = (const float*)d_in[12];
  p.bih2 = (const float*)d_in[13]; p.bhh2 = (const float*)d_in[14];
  p.wih3 = (const float*)d_in[15]; p.whh3 = (const float*)d_in[16];
  p.bih3 = (const float*)d_in[17]; p.bhh3 = (const float*)d_in[18];
  p.wwin = (const float*)d_in[19]; p.bwin = (const float*)d_in[20];
  p.wout = (const float*)d_in[21]; p.bout = (const float*)d_in[22];
  float* out = (float*)d_out;
  p.out_y  = out;
  p.out_wv = out + (size_t)B_*T_*OUT_;
  p.out_kap = p.out_wv + (size_t)B_*T_*V_;
  char* ws = (char*)d_ws;
  p.flags = (u32*)(ws + FLAGS_B);
  p.w1f = (u32*)(ws + W1F_B);
  p.w2f = (u32*)(ws + W2F_B);
  p.w3f = (u32*)(ws + W3F_B);
  p.wof = (u32*)(ws + WOF_B);
  p.wwf = (u32*)(ws + WWF_B);
  p.fwv = (u32*)(ws + FWV_B);
  p.fh1 = (u32*)(ws + FH1_B);
  p.fh2 = (u32*)(ws + FH2_B);
  p.fh3 = (u32*)(ws + FH3_B);
  p.pg2 = (u32*)(ws + PG2_B);
  p.pg3 = (u32*)(ws + PG3_B);
  (void)hipMemsetAsync(ws + FLAGS_B, 0, FLAGS_SZ, stream);
  hipLaunchKernelGGL(hw_pipe2, dim3(NBLK), dim3(THR), 0, stream, p);
}